// Round 1
// baseline (523.115 us; speedup 1.0000x reference)
//
#include <hip/hip_runtime.h>
#include <math.h>

#define N_DIM 32
#define C_DIM 512
#define K_DIM 64
#define P_DIM 3136

// ws layout (floats): wt 32768 | a_t 6422528 | asum 2048 | asum_part 28672 |
//                     gsum 32 | ssb 16384 | part S*1048576
// S=14 -> 84.8 MB, S=7 -> 55.4 MB, S=2 -> 34.1 MB (selected from ws_size)

// ---------------- prep: wt[c][k] = conv_w[k][c] ----------------
__global__ __launch_bounds__(256) void k_prep(const float* __restrict__ conv_w,
                                              float* __restrict__ wt) {
    const int b = blockIdx.x, t = threadIdx.x;
#pragma unroll
    for (int r = 0; r < 4; ++r) {
        int idx = b * 1024 + r * 256 + t;      // 0..32767
        int c = idx >> 6, k = idx & 63;
        wt[idx] = conv_w[k * C_DIM + c];
    }
}

// ---------------- GEMM1 + softmax + asum partials: a_t[n][p][k] ----------------
// block: 224 pixels x 64 k (14 exact tiles); 512 threads (8 waves), thread: 7p x 4k.
// 64-channel LDS chunks, register-prefetch double buffering. NO global atomics.
// Rationale vs prior version: 256-thread/4-wave blocks at grid=448 capped occupancy
// at ~17% (grid-limited); 8 waves/block -> 16 waves/CU ceiling (2 blocks/CU, 74KB LDS).
__global__ __launch_bounds__(512) void k_logits(const float* __restrict__ x,
                                                const float* __restrict__ wt,
                                                const float* __restrict__ bias,
                                                float* __restrict__ a_t,
                                                float* __restrict__ asum_part) {
    __shared__ float xs[64][224];   // 56 KB, [c][p]
    __shared__ float wsh[64][64];   // 16 KB, [c][k]
    __shared__ float asl[8][64];    //  2 KB
    const int tid = threadIdx.x;
    const int n  = blockIdx.y;
    const int pblk = blockIdx.x;
    const int p0 = pblk * 224;
    const int tp = tid >> 4;        // 0..31 -> pixels p0 + tp + 32*i, i<7
    const int tk = tid & 15;        // 0..15 -> k = tk*4..+4

    float acc[7][4];
    {
        float4 b0 = *(const float4*)(bias + tk * 4);
        float br[4] = {b0.x, b0.y, b0.z, b0.w};
#pragma unroll
        for (int i = 0; i < 7; ++i)
#pragma unroll
            for (int j = 0; j < 4; ++j) acc[i][j] = br[j];
    }

    const float* xn = x + (size_t)n * C_DIM * P_DIM + p0;

    float4 xv[7], wv[2];
#pragma unroll
    for (int i = 0; i < 7; ++i) {
        int f = tid + 512 * i;      // 0..3583 = 64 c-rows x 56 float4
        xv[i] = *(const float4*)(xn + (size_t)(f / 56) * P_DIM + (f % 56) * 4);
    }
#pragma unroll
    for (int i = 0; i < 2; ++i) {
        int f = tid + 512 * i;      // 0..1023 = 64 rows x 16 float4
        wv[i] = *(const float4*)(wt + (f >> 4) * K_DIM + (f & 15) * 4);
    }

    for (int cc = 0; cc < C_DIM; cc += 64) {
        __syncthreads();
#pragma unroll
        for (int i = 0; i < 7; ++i) {
            int f = tid + 512 * i;
            *(float4*)&xs[f / 56][(f % 56) * 4] = xv[i];
        }
#pragma unroll
        for (int i = 0; i < 2; ++i) {
            int f = tid + 512 * i;
            *(float4*)&wsh[f >> 4][(f & 15) * 4] = wv[i];
        }
        __syncthreads();

        if (cc + 64 < C_DIM) {
            const float* xc = xn + (size_t)(cc + 64) * P_DIM;
#pragma unroll
            for (int i = 0; i < 7; ++i) {
                int f = tid + 512 * i;
                xv[i] = *(const float4*)(xc + (size_t)(f / 56) * P_DIM + (f % 56) * 4);
            }
            const float* wc = wt + (cc + 64) * K_DIM;
#pragma unroll
            for (int i = 0; i < 2; ++i) {
                int f = tid + 512 * i;
                wv[i] = *(const float4*)(wc + (f >> 4) * K_DIM + (f & 15) * 4);
            }
        }

#pragma unroll 8
        for (int c = 0; c < 64; ++c) {
            float xr[7];
#pragma unroll
            for (int i = 0; i < 7; ++i) xr[i] = xs[c][tp + 32 * i];   // 16-lane broadcast
            float4 w0 = *(const float4*)&wsh[c][tk * 4];
            float wr[4] = {w0.x, w0.y, w0.z, w0.w};
#pragma unroll
            for (int i = 0; i < 7; ++i)
#pragma unroll
                for (int j = 0; j < 4; ++j)
                    acc[i][j] = fmaf(xr[i], wr[j], acc[i][j]);
        }
    }

    // softmax per pixel: 64 k live in the 16 lanes sharing tp (xor 1,2,4,8)
    float sk[4] = {0.f, 0.f, 0.f, 0.f};
#pragma unroll
    for (int i = 0; i < 7; ++i) {
        float m = fmaxf(fmaxf(acc[i][0], acc[i][1]), fmaxf(acc[i][2], acc[i][3]));
        m = fmaxf(m, __shfl_xor(m, 1));
        m = fmaxf(m, __shfl_xor(m, 2));
        m = fmaxf(m, __shfl_xor(m, 4));
        m = fmaxf(m, __shfl_xor(m, 8));
        float e0 = __expf(acc[i][0] - m);
        float e1 = __expf(acc[i][1] - m);
        float e2 = __expf(acc[i][2] - m);
        float e3 = __expf(acc[i][3] - m);
        float s = (e0 + e1) + (e2 + e3);
        s += __shfl_xor(s, 1);
        s += __shfl_xor(s, 2);
        s += __shfl_xor(s, 4);
        s += __shfl_xor(s, 8);
        const float inv = 1.0f / s;
        float4 o;
        o.x = e0 * inv; o.y = e1 * inv; o.z = e2 * inv; o.w = e3 * inv;
        float* ap = a_t + ((size_t)n * P_DIM + p0 + tp + 32 * i) * K_DIM + tk * 4;
        *(float4*)ap = o;
        sk[0] += o.x; sk[1] += o.y; sk[2] += o.z; sk[3] += o.w;
    }
    // reduce over tp-within-wave (lane bits 4,5), then across the 8 waves via LDS
#pragma unroll
    for (int j = 0; j < 4; ++j) {
        sk[j] += __shfl_xor(sk[j], 16);
        sk[j] += __shfl_xor(sk[j], 32);
    }
    const int lane = tid & 63, wid = tid >> 6;
    if (lane < 16) {
#pragma unroll
        for (int j = 0; j < 4; ++j) asl[wid][lane * 4 + j] = sk[j];
    }
    __syncthreads();
    if (tid < 64) {
        float s = 0.f;
#pragma unroll
        for (int w = 0; w < 8; ++w) s += asl[w][tid];
        asum_part[((size_t)n * 14 + pblk) * K_DIM + tid] = s;
    }
}

// ---------------- asum[n][k] = sum_b asum_part[n][b][k] ----------------
__global__ __launch_bounds__(256) void k_red(const float* __restrict__ asum_part,
                                             float* __restrict__ asum) {
    const int idx = blockIdx.x * 256 + threadIdx.x;   // 0..2047
    const int n = idx >> 6, k = idx & 63;
    float s = 0.f;
#pragma unroll
    for (int b = 0; b < 14; ++b)
        s += asum_part[((size_t)n * 14 + b) * K_DIM + k];
    asum[idx] = s;
}

// ---------------- GEMM2: part[s][n][c][k] = sum_{p in slice s} x[n][c][p]*a_t[n][p][k] ----
// block: 128c x 64k, 128 threads, 8x8/thread; plain stores (no atomics);
// register-prefetch double buffering over 16-p chunks.
__global__ __launch_bounds__(128) void k_gemm2(const float* __restrict__ x,
                                               const float* __restrict__ a_t,
                                               float* __restrict__ part,
                                               int pslice) {
    __shared__ float xs[16][132];   // [p][c], pad 128->132 (stores 2-way max)
    __shared__ float as[16][64];    // [p][k]
    const int tid = threadIdx.x;
    const int c0 = blockIdx.x * 128;
    const int n  = blockIdx.y;
    const int s  = blockIdx.z;
    const int p0 = s * pslice;
    const int tc = tid >> 3;        // 0..15 -> c = c0 + tc*8
    const int tk = tid & 7;         // 0..7  -> k = tk*8

    float acc[8][8];
#pragma unroll
    for (int i = 0; i < 8; ++i)
#pragma unroll
        for (int j = 0; j < 8; ++j) acc[i][j] = 0.f;

    const float* xb = x + ((size_t)n * C_DIM + c0) * P_DIM + p0;
    const float* ab = a_t + ((size_t)n * P_DIM + p0) * K_DIM;

    float4 xv[4], av[2];
#pragma unroll
    for (int i = 0; i < 4; ++i) {
        int f = tid + 128 * i;
        xv[i] = *(const float4*)(xb + (size_t)(f >> 2) * P_DIM + (f & 3) * 4);
    }
#pragma unroll
    for (int i = 0; i < 2; ++i) {
        int f = tid + 128 * i;
        av[i] = *(const float4*)(ab + (size_t)(f >> 4) * K_DIM + (f & 15) * 4);
    }

    for (int pb = 0; pb < pslice; pb += 16) {
        __syncthreads();
#pragma unroll
        for (int i = 0; i < 4; ++i) {
            int f = tid + 128 * i;
            int c = f >> 2, pe = (f & 3) * 4;
            xs[pe + 0][c] = xv[i].x;
            xs[pe + 1][c] = xv[i].y;
            xs[pe + 2][c] = xv[i].z;
            xs[pe + 3][c] = xv[i].w;
        }
#pragma unroll
        for (int i = 0; i < 2; ++i) {
            int f = tid + 128 * i;
            *(float4*)&as[f >> 4][(f & 15) * 4] = av[i];
        }
        __syncthreads();

        if (pb + 16 < pslice) {
            const float* xc = xb + pb + 16;
            const float* ac = ab + (size_t)(pb + 16) * K_DIM;
#pragma unroll
            for (int i = 0; i < 4; ++i) {
                int f = tid + 128 * i;
                xv[i] = *(const float4*)(xc + (size_t)(f >> 2) * P_DIM + (f & 3) * 4);
            }
#pragma unroll
            for (int i = 0; i < 2; ++i) {
                int f = tid + 128 * i;
                av[i] = *(const float4*)(ac + (size_t)(f >> 4) * K_DIM + (f & 15) * 4);
            }
        }

#pragma unroll 4
        for (int p = 0; p < 16; ++p) {
            float4 x0 = *(const float4*)&xs[p][tc * 8];
            float4 x1 = *(const float4*)&xs[p][tc * 8 + 4];
            float4 a0 = *(const float4*)&as[p][tk * 8];
            float4 a1 = *(const float4*)&as[p][tk * 8 + 4];
            float xr[8] = {x0.x, x0.y, x0.z, x0.w, x1.x, x1.y, x1.z, x1.w};
            float ar[8] = {a0.x, a0.y, a0.z, a0.w, a1.x, a1.y, a1.z, a1.w};
#pragma unroll
            for (int i = 0; i < 8; ++i)
#pragma unroll
                for (int j = 0; j < 8; ++j)
                    acc[i][j] = fmaf(xr[i], ar[j], acc[i][j]);
        }
    }

    float* po = part + (((size_t)s * N_DIM + n) * C_DIM + c0 + tc * 8) * K_DIM + tk * 8;
#pragma unroll
    for (int i = 0; i < 8; ++i) {
        float4 o0, o1;
        o0.x = acc[i][0]; o0.y = acc[i][1]; o0.z = acc[i][2]; o0.w = acc[i][3];
        o1.x = acc[i][4]; o1.y = acc[i][5]; o1.z = acc[i][6]; o1.w = acc[i][7];
        *(float4*)&po[(size_t)i * K_DIM] = o0;
        *(float4*)&po[(size_t)i * K_DIM + 4] = o1;
    }
}

// ---------------- slice-reduce + subtract + intra-norm over k; ss -> ssb (no atomics) ----
template <int S>
__global__ __launch_bounds__(256) void k_intra(const float* __restrict__ part,
                                               const float* __restrict__ cent,
                                               const float* __restrict__ asum,
                                               float* __restrict__ out,
                                               float* __restrict__ ssb) {
    const int w = (blockIdx.x * 256 + threadIdx.x) >> 6;  // (n,c) wave id
    const int lane = threadIdx.x & 63;
    const int n = w >> 9;
    const int c = w & 511;
    const size_t off = ((size_t)n * C_DIM + c) * K_DIM + lane;
    const size_t stride = (size_t)N_DIM * C_DIM * K_DIM;

    float v = 0.f;
#pragma unroll
    for (int s = 0; s < S; ++s) v += part[s * stride + off];
    // cent_r[c][k] = centroids_flat[c*64 + k] (row-major reshape, NOT transpose)
    v -= cent[c * K_DIM + lane] * asum[n * K_DIM + lane];

    float ss = v * v;
#pragma unroll
    for (int o = 32; o > 0; o >>= 1) ss += __shfl_xor(ss, o);

    const float denom = fmaxf(sqrtf(ss), 1e-12f);
    out[off] = v / denom;
    if (lane == 0) ssb[w] = ss / (denom * denom);   // == clipped ratio, sums to gsum
}

// ---------------- gsum[n] = sum_c ssb[n][c] ----------------
__global__ __launch_bounds__(256) void k_gsum(const float* __restrict__ ssb,
                                              float* __restrict__ gsum) {
    const int n = blockIdx.x, t = threadIdx.x;
    float s = ssb[n * C_DIM + t] + ssb[n * C_DIM + t + 256];
    __shared__ float red[256];
    red[t] = s;
    __syncthreads();
    for (int o = 128; o > 0; o >>= 1) {
        if (t < o) red[t] += red[t + o];
        __syncthreads();
    }
    if (t == 0) gsum[n] = red[0];
}

// ---------------- final global L2 normalization ----------------
__global__ __launch_bounds__(256) void k_final(float* __restrict__ out,
                                               const float* __restrict__ gsum) {
    const size_t i = (size_t)blockIdx.x * 256 + threadIdx.x;  // 0 .. 2^20-1
    const int n = (int)(i >> 15);                             // C*K = 32768
    const float g = sqrtf(gsum[n]);
    out[i] = out[i] / fmaxf(g, 1e-12f);
}

extern "C" void kernel_launch(void* const* d_in, const int* in_sizes, int n_in,
                              void* d_out, int out_size, void* d_ws, size_t ws_size,
                              hipStream_t stream) {
    const float* x      = (const float*)d_in[0];  // (32,512,56,56)
    const float* cent   = (const float*)d_in[1];  // (64,512) flat
    const float* conv_w = (const float*)d_in[2];  // (64,512)
    const float* conv_b = (const float*)d_in[3];  // (64,)

    float* ws    = (float*)d_ws;
    float* wt    = ws;                                     // 32768
    float* a_t   = wt + 32768;                             // 32*3136*64
    float* asum  = a_t + (size_t)N_DIM * P_DIM * K_DIM;    // 2048
    float* apart = asum + 2048;                            // 32*14*64 = 28672
    float* gsum  = apart + 28672;                          // 32
    float* ssb   = gsum + 32;                              // 16384
    float* part  = ssb + 16384;                            // S * 1048576
    float* out   = (float*)d_out;

    const size_t base_f = (size_t)(part - ws);
    const size_t cxk = (size_t)N_DIM * C_DIM * K_DIM;      // 1048576
    int S = 14;
    if (ws_size < (base_f + 14 * cxk) * 4) S = 7;
    if (ws_size < (base_f + 7 * cxk) * 4) S = 2;
    const int pslice = P_DIM / S;

    hipLaunchKernelGGL(k_prep,   dim3(32),        dim3(256), 0, stream, conv_w, wt);
    hipLaunchKernelGGL(k_logits, dim3(14, 32),    dim3(512), 0, stream, x, wt, conv_b, a_t, apart);
    hipLaunchKernelGGL(k_red,    dim3(8),         dim3(256), 0, stream, apart, asum);
    hipLaunchKernelGGL(k_gemm2,  dim3(4, 32, S),  dim3(128), 0, stream, x, a_t, part, pslice);
    if (S == 14)
        hipLaunchKernelGGL(k_intra<14>, dim3(4096), dim3(256), 0, stream, part, cent, asum, out, ssb);
    else if (S == 7)
        hipLaunchKernelGGL(k_intra<7>,  dim3(4096), dim3(256), 0, stream, part, cent, asum, out, ssb);
    else
        hipLaunchKernelGGL(k_intra<2>,  dim3(4096), dim3(256), 0, stream, part, cent, asum, out, ssb);
    hipLaunchKernelGGL(k_gsum,   dim3(32),        dim3(256), 0, stream, ssb, gsum);
    hipLaunchKernelGGL(k_final,  dim3(4096),      dim3(256), 0, stream, out, gsum);
}